// Round 1
// baseline (593.176 us; speedup 1.0000x reference)
//
#include <hip/hip_runtime.h>

#define N_ATOMS 4096
#define FDIM 32
#define HID 512

typedef __bf16 bf16x8 __attribute__((ext_vector_type(8)));
typedef float f32x4 __attribute__((ext_vector_type(4)));

__device__ __forceinline__ float bf2f(ushort h) {
  union { uint u; float f; } v; v.u = ((uint)h) << 16; return v.f;
}
__device__ __forceinline__ ushort f2bf(float f) {
  union { float f; uint u; } v; v.f = f;
  uint u = v.u;
  u += 0x7fffu + ((u >> 16) & 1u);   // RNE
  return (ushort)(u >> 16);
}

// async global->LDS, 16B per lane; LDS dest must be linear: base + lane*16
__device__ __forceinline__ void gload16(const ushort* g, ushort* l) {
  __builtin_amdgcn_global_load_lds(
      (const __attribute__((address_space(1))) void*)g,
      (__attribute__((address_space(3))) void*)l,
      16, 0, 0);
}

// ---- prep_adj: adjb = bf16(adj); rdeg[i] = 1/max(rowsum_f32, 1) -----------
__global__ __launch_bounds__(256) void prep_adj(const float* __restrict__ adj,
                                                ushort* __restrict__ adjb,
                                                float* __restrict__ rdeg) {
  const int row = blockIdx.x;
  const int t = threadIdx.x;
  const float* r = adj + (size_t)row * N_ATOMS;
  ushort* w = adjb + (size_t)row * N_ATOMS;
  float s = 0.f;
#pragma unroll
  for (int i = 0; i < 4; i++) {
    const int c = (t + i * 256) * 4;
    float4 v = *(const float4*)(r + c);
    s += v.x + v.y + v.z + v.w;
    ushort4 o;
    o.x = f2bf(v.x); o.y = f2bf(v.y); o.z = f2bf(v.z); o.w = f2bf(v.w);
    *(ushort4*)(w + c) = o;
  }
#pragma unroll
  for (int off = 32; off; off >>= 1) s += __shfl_down(s, off);
  __shared__ float red[4];
  if ((t & 63) == 0) red[t >> 6] = s;
  __syncthreads();
  if (t == 0) rdeg[row] = 1.f / fmaxf(red[0] + red[1] + red[2] + red[3], 1.f);
}

// ---- xt[c][m] = bf16(x[m][c]) ---------------------------------------------
__global__ __launch_bounds__(256) void prep_x(const float* __restrict__ x,
                                              ushort* __restrict__ xt) {
  const int idx = blockIdx.x * 256 + threadIdx.x;   // 4096*32
  const int m = idx >> 5, c = idx & 31;
  xt[(size_t)c * N_ATOMS + m] = f2bf(x[(size_t)m * FDIM + c]);
}

// ---- wcat2[n][0:512]=Ws2[n], [512:1024]=Wn2[n] (bf16) ---------------------
__global__ __launch_bounds__(256) void prep_w2(const float* __restrict__ ws2,
                                               const float* __restrict__ wn2,
                                               ushort* __restrict__ wcat2) {
  const int idx = blockIdx.x * 256 + threadIdx.x;   // 512*1024
  const int n = idx >> 10, k = idx & 1023;
  float v = (k < 512) ? ws2[(size_t)n * 512 + k] : wn2[(size_t)n * 512 + k - 512];
  wcat2[idx] = f2bf(v);
}

// ---- m97-structure NT MFMA GEMM, split-K atomic f32 -----------------------
// C[m,n] += sum_k A[m,k]*Bt[n,k] ; staging via global_load_lds width=16,
// linear LDS pitch 64 (no pad: gload_lds needs contiguous lane order).
template<int BM, int BN, int WROWS, int WCOLS>
__global__ __launch_bounds__(256, 2) void gemm_nt(
    const ushort* __restrict__ A, int lda,
    const ushort* __restrict__ B, int ldb,
    int Kchunk, float* __restrict__ Cout, int ldc)
{
  constexpr int WTM = BM / WROWS;
  constexpr int WTN = BN / WCOLS;
  constexpr int MT = WTM / 16;
  constexpr int NT = WTN / 16;
  constexpr int AL = BM / 32;     // global_load_lds insts per wave for A tile
  constexpr int BL = BN / 32;

  __shared__ __align__(16) ushort As[BM * 64];
  __shared__ __align__(16) ushort Bs[BN * 64];

  const int t = threadIdx.x;
  const int wave = t >> 6;
  const int lane = t & 63;
  const int q = lane >> 4;
  const int ln = lane & 15;
  const int wr = wave / WCOLS;
  const int wc = wave % WCOLS;
  const int mbase = wr * WTM;
  const int nbase = wc * WTN;

  const int n0 = blockIdx.x * BN;
  const int m0 = blockIdx.y * BM;
  const int kbase = blockIdx.z * Kchunk;

  f32x4 acc[MT][NT];
#pragma unroll
  for (int i = 0; i < MT; i++)
#pragma unroll
    for (int j = 0; j < NT; j++)
#pragma unroll
      for (int r = 0; r < 4; r++) acc[i][j][r] = 0.f;

  for (int kt = 0; kt < Kchunk; kt += 64) {
    const int kg = kbase + kt;
#pragma unroll
    for (int i = 0; i < AL; i++) {
      const int g = (wave * AL + i) * 64 + lane;   // 16B chunk idx; linear in lane
      const int row = g >> 3, c8 = g & 7;          // 8 chunks per 64-col row
      gload16(A + (size_t)(m0 + row) * lda + kg + c8 * 8, &As[g * 8]);
    }
#pragma unroll
    for (int i = 0; i < BL; i++) {
      const int g = (wave * BL + i) * 64 + lane;
      const int row = g >> 3, c8 = g & 7;
      gload16(B + (size_t)(n0 + row) * ldb + kg + c8 * 8, &Bs[g * 8]);
    }
    __syncthreads();   // compiler emits vmcnt(0) drain here -> LDS valid
#pragma unroll
    for (int kk = 0; kk < 64; kk += 32) {
      bf16x8 af[MT], bfr[NT];
#pragma unroll
      for (int i = 0; i < MT; i++)
        af[i] = *(const bf16x8*)(&As[(mbase + i * 16 + ln) * 64 + kk + q * 8]);
#pragma unroll
      for (int j = 0; j < NT; j++)
        bfr[j] = *(const bf16x8*)(&Bs[(nbase + j * 16 + ln) * 64 + kk + q * 8]);
#pragma unroll
      for (int i = 0; i < MT; i++)
#pragma unroll
        for (int j = 0; j < NT; j++)
          acc[i][j] = __builtin_amdgcn_mfma_f32_16x16x32_bf16(af[i], bfr[j], acc[i][j], 0, 0, 0);
    }
    __syncthreads();
  }

#pragma unroll
  for (int i = 0; i < MT; i++)
#pragma unroll
    for (int j = 0; j < NT; j++)
#pragma unroll
      for (int r = 0; r < 4; r++) {
        const int m = m0 + mbase + i * 16 + q * 4 + r;   // C/D: row=(lane>>4)*4+reg
        const int n = n0 + nbase + j * 16 + ln;          //      col=lane&15
        atomicAdd(Cout + (size_t)m * ldc + n, acc[i][j][r]);
      }
}

// ---- agg2 epilogue: cat2[m][512+n] = bf16(agg2f[m][n] * rdeg[m]) ----------
__global__ __launch_bounds__(256) void epi_agg2(const float* __restrict__ gf,
                                                const float* __restrict__ rdeg,
                                                ushort* __restrict__ cat2) {
  const int idx = blockIdx.x * 256 + threadIdx.x;   // 4096*128 (x4 elems)
  const int m = idx >> 7;
  const int n4 = (idx & 127) * 4;
  const float r = rdeg[m];
  float4 v = *(const float4*)(gf + (size_t)m * HID + n4);
  ushort4 o;
  o.x = f2bf(v.x * r); o.y = f2bf(v.y * r);
  o.z = f2bf(v.z * r); o.w = f2bf(v.w * r);
  *(ushort4*)(cat2 + (size_t)m * 1024 + 512 + n4) = o;
}

// ---- h1 = relu(x Ws1^T + (agg1*rdeg) Wn1^T + b) (all f32 in, bf16 out) ----
__global__ __launch_bounds__(256) void h1_kernel(
    const float* __restrict__ x, const float* __restrict__ agg1,
    const float* __restrict__ rdeg,
    const float* __restrict__ ws1, const float* __restrict__ bs1,
    const float* __restrict__ wn1, const float* __restrict__ bn1,
    ushort* __restrict__ cat2, ushort* __restrict__ h1t)
{
  const int idx = blockIdx.x * 256 + threadIdx.x;   // 4096*512
  const int m = idx >> 9;
  const int n = idx & 511;
  const float* xr = x + (size_t)m * FDIM;
  const float* ar = agg1 + (size_t)m * FDIM;
  const float* w1 = ws1 + (size_t)n * FDIM;
  const float* w2 = wn1 + (size_t)n * FDIM;
  float accs = 0.f, accn = 0.f;
#pragma unroll
  for (int k = 0; k < FDIM; k += 4) {
    float4 xv = *(const float4*)(xr + k);
    float4 av = *(const float4*)(ar + k);
    float4 wv = *(const float4*)(w1 + k);
    float4 nv = *(const float4*)(w2 + k);
    accs += xv.x * wv.x + xv.y * wv.y + xv.z * wv.z + xv.w * wv.w;
    accn += av.x * nv.x + av.y * nv.y + av.z * nv.z + av.w * nv.w;
  }
  float v = fmaxf(accs + accn * rdeg[m] + bs1[n] + bn1[n], 0.f);
  ushort h = f2bf(v);
  cat2[(size_t)m * 1024 + n] = h;
  h1t[(size_t)n * N_ATOMS + m] = h;
}

// ---- heads: fused h2 = relu(h2f + b) read; atom logits + bond a/b ---------
__global__ __launch_bounds__(256) void heads_kernel(
    const float* __restrict__ h2f,
    const float* __restrict__ bs2, const float* __restrict__ bn2,
    const float* __restrict__ w_atom, const float* __restrict__ b_atom,
    const float* __restrict__ w_bond,
    float* __restrict__ atom_out,
    float* __restrict__ a_buf, float* __restrict__ b_buf)
{
  const int idx = blockIdx.x * 256 + threadIdx.x;
  if (idx >= N_ATOMS * 40) return;
  const int m = idx / 40;
  const int c = idx - m * 40;
  const float* hr = h2f + (size_t)m * HID;
  const float* wr;
  if (c < 32)      wr = w_atom + (size_t)c * HID;
  else if (c < 36) wr = w_bond + (size_t)(c - 32) * 1024;        // a: W[:, :H]
  else             wr = w_bond + (size_t)(c - 36) * 1024 + 512;  // b: W[:, H:]
  float acc = 0.f;
#pragma unroll 4
  for (int k = 0; k < HID; k += 4) {
    float4 hv = *(const float4*)(hr + k);
    float4 s0 = *(const float4*)(bs2 + k);
    float4 s1 = *(const float4*)(bn2 + k);
    float4 w0 = *(const float4*)(wr + k);
    acc += fmaxf(hv.x + s0.x + s1.x, 0.f) * w0.x
         + fmaxf(hv.y + s0.y + s1.y, 0.f) * w0.y
         + fmaxf(hv.z + s0.z + s1.z, 0.f) * w0.z
         + fmaxf(hv.w + s0.w + s1.w, 0.f) * w0.w;
  }
  if (c < 32)      atom_out[(size_t)m * 32 + c] = acc + b_atom[c];
  else if (c < 36) a_buf[(size_t)m * 4 + (c - 32)] = acc;
  else             b_buf[(size_t)m * 4 + (c - 36)] = acc;
}

// ---- bond fill: out[i][j][0:4] (f32), diagonal explicitly zeroed ----------
__global__ __launch_bounds__(256) void bond_fill(
    const float* __restrict__ av, const float* __restrict__ bv,
    const float* __restrict__ bbond, float* __restrict__ out)
{
  const int idx = blockIdx.x * 256 + threadIdx.x;  // 4096*4096
  const int i = idx >> 12;
  const int j = idx & 4095;
  float4 r;
  if (i < j) {
    float4 ai = *(const float4*)(av + (size_t)i * 4);
    float4 bj = *(const float4*)(bv + (size_t)j * 4);
    r.x = ai.x + bj.x + bbond[0]; r.y = ai.y + bj.y + bbond[1];
    r.z = ai.z + bj.z + bbond[2]; r.w = ai.w + bj.w + bbond[3];
  } else if (i > j) {
    float4 aj = *(const float4*)(av + (size_t)j * 4);
    float4 bi = *(const float4*)(bv + (size_t)i * 4);
    r.x = aj.x + bi.x + bbond[0]; r.y = aj.y + bi.y + bbond[1];
    r.z = aj.z + bi.z + bbond[2]; r.w = aj.w + bi.w + bbond[3];
  } else {
    r.x = r.y = r.z = r.w = 0.f;   // diagonal stays zero (d_out is poisoned!)
  }
  *(float4*)(out + (size_t)idx * 4) = r;
}

extern "C" void kernel_launch(void* const* d_in, const int* in_sizes, int n_in,
                              void* d_out, int out_size, void* d_ws, size_t ws_size,
                              hipStream_t stream)
{
  const float* x        = (const float*)d_in[0];
  const float* adj      = (const float*)d_in[1];
  const float* w_self1  = (const float*)d_in[2];
  const float* b_self1  = (const float*)d_in[3];
  const float* w_neigh1 = (const float*)d_in[4];
  const float* b_neigh1 = (const float*)d_in[5];
  const float* w_self2  = (const float*)d_in[6];
  const float* b_self2  = (const float*)d_in[7];
  const float* w_neigh2 = (const float*)d_in[8];
  const float* b_neigh2 = (const float*)d_in[9];
  const float* w_atom   = (const float*)d_in[10];
  const float* b_atom   = (const float*)d_in[11];
  const float* w_bond   = (const float*)d_in[12];
  const float* b_bond   = (const float*)d_in[13];

  char* w = (char*)d_ws;
  float*  rdeg  = (float*)w;  w += (size_t)N_ATOMS * sizeof(float);
  float*  agg1  = (float*)w;  w += (size_t)N_ATOMS * FDIM * sizeof(float);
  float*  a_buf = (float*)w;  w += (size_t)N_ATOMS * 4 * sizeof(float);
  float*  b_buf = (float*)w;  w += (size_t)N_ATOMS * 4 * sizeof(float);
  ushort* adjb  = (ushort*)w; w += (size_t)N_ATOMS * N_ATOMS * sizeof(ushort);
  ushort* xt    = (ushort*)w; w += (size_t)FDIM * N_ATOMS * sizeof(ushort);
  ushort* h1t   = (ushort*)w; w += (size_t)HID * N_ATOMS * sizeof(ushort);
  ushort* cat2  = (ushort*)w; w += (size_t)N_ATOMS * 1024 * sizeof(ushort);
  ushort* wcat2 = (ushort*)w; w += (size_t)HID * 1024 * sizeof(ushort);
  float*  gf    = (float*)w;  w += (size_t)N_ATOMS * HID * sizeof(float); // shared agg2f/h2f

  float* atom_out = (float*)d_out;
  float* bond_out = (float*)d_out + (size_t)N_ATOMS * FDIM;

  prep_adj<<<N_ATOMS, 256, 0, stream>>>(adj, adjb, rdeg);
  prep_x<<<(N_ATOMS * FDIM) / 256, 256, 0, stream>>>(x, xt);
  prep_w2<<<(HID * 1024) / 256, 256, 0, stream>>>(w_self2, w_neigh2, wcat2);
  hipMemsetAsync(agg1, 0, (size_t)N_ATOMS * FDIM * sizeof(float), stream);
  hipMemsetAsync(gf, 0, (size_t)N_ATOMS * HID * sizeof(float), stream);

  // agg1 partials: M=4096 N=32 K=4096, split-K=16 -> 512 blocks (2/CU)
  gemm_nt<128, 32, 4, 1><<<dim3(1, 32, 16), 256, 0, stream>>>(
      adjb, N_ATOMS, xt, N_ATOMS, 256, agg1, FDIM);
  h1_kernel<<<(N_ATOMS * HID) / 256, 256, 0, stream>>>(
      x, agg1, rdeg, w_self1, b_self1, w_neigh1, b_neigh1, cat2, h1t);
  // agg2 = adj @ h1 (unscaled): M=4096 N=512 K=4096, split-K=4 -> 512 blocks
  gemm_nt<128, 128, 2, 2><<<dim3(4, 32, 4), 256, 0, stream>>>(
      adjb, N_ATOMS, h1t, N_ATOMS, 1024, gf, HID);
  epi_agg2<<<(N_ATOMS * HID / 4) / 256, 256, 0, stream>>>(gf, rdeg, cat2);
  hipMemsetAsync(gf, 0, (size_t)N_ATOMS * HID * sizeof(float), stream);
  // h2f = cat2 @ [Ws2|Wn2]^T : M=4096 N=512 K=1024, split-K=4 -> 512 blocks
  gemm_nt<128, 128, 2, 2><<<dim3(4, 32, 4), 256, 0, stream>>>(
      cat2, 1024, wcat2, 1024, 256, gf, HID);
  heads_kernel<<<(N_ATOMS * 40 + 255) / 256, 256, 0, stream>>>(
      gf, b_self2, b_neigh2, w_atom, b_atom, w_bond, atom_out, a_buf, b_buf);
  bond_fill<<<(N_ATOMS * N_ATOMS) / 256, 256, 0, stream>>>(a_buf, b_buf, b_bond, bond_out);
}

// Round 2
// 557.585 us; speedup vs baseline: 1.0638x; 1.0638x over previous
//
#include <hip/hip_runtime.h>

#define N_ATOMS 4096
#define FDIM 32
#define HID 512

typedef __bf16 bf16x8 __attribute__((ext_vector_type(8)));
typedef float f32x4 __attribute__((ext_vector_type(4)));

__device__ __forceinline__ float bf2f(ushort h) {
  union { uint u; float f; } v; v.u = ((uint)h) << 16; return v.f;
}
__device__ __forceinline__ ushort f2bf(float f) {
  union { float f; uint u; } v; v.f = f;
  uint u = v.u;
  u += 0x7fffu + ((u >> 16) & 1u);   // RNE
  return (ushort)(u >> 16);
}

// async global->LDS, 16B per lane; LDS dest must be linear: base + lane*16
__device__ __forceinline__ void gload16(const ushort* g, ushort* l) {
  __builtin_amdgcn_global_load_lds(
      (const __attribute__((address_space(1))) void*)g,
      (__attribute__((address_space(3))) void*)l,
      16, 0, 0);
}

// ---- prep_adj: adjb = bf16(adj); rdeg[i] = 1/max(rowsum_f32, 1) -----------
__global__ __launch_bounds__(256) void prep_adj(const float* __restrict__ adj,
                                                ushort* __restrict__ adjb,
                                                float* __restrict__ rdeg) {
  const int row = blockIdx.x;
  const int t = threadIdx.x;
  const float* r = adj + (size_t)row * N_ATOMS;
  ushort* w = adjb + (size_t)row * N_ATOMS;
  float s = 0.f;
#pragma unroll
  for (int i = 0; i < 4; i++) {
    const int c = (t + i * 256) * 4;
    float4 v = *(const float4*)(r + c);
    s += v.x + v.y + v.z + v.w;
    ushort4 o;
    o.x = f2bf(v.x); o.y = f2bf(v.y); o.z = f2bf(v.z); o.w = f2bf(v.w);
    *(ushort4*)(w + c) = o;
  }
#pragma unroll
  for (int off = 32; off; off >>= 1) s += __shfl_down(s, off);
  __shared__ float red[4];
  if ((t & 63) == 0) red[t >> 6] = s;
  __syncthreads();
  if (t == 0) rdeg[row] = 1.f / fmaxf(red[0] + red[1] + red[2] + red[3], 1.f);
}

// ---- xt[c][m] = bf16(x[m][c]) ---------------------------------------------
__global__ __launch_bounds__(256) void prep_x(const float* __restrict__ x,
                                              ushort* __restrict__ xt) {
  const int idx = blockIdx.x * 256 + threadIdx.x;   // 4096*32
  const int m = idx >> 5, c = idx & 31;
  xt[(size_t)c * N_ATOMS + m] = f2bf(x[(size_t)m * FDIM + c]);
}

// ---- wcat2[n][0:512]=Ws2[n], [512:1024]=Wn2[n] (bf16) ---------------------
__global__ __launch_bounds__(256) void prep_w2(const float* __restrict__ ws2,
                                               const float* __restrict__ wn2,
                                               ushort* __restrict__ wcat2) {
  const int idx = blockIdx.x * 256 + threadIdx.x;   // 512*1024
  const int n = idx >> 10, k = idx & 1023;
  float v = (k < 512) ? ws2[(size_t)n * 512 + k] : wn2[(size_t)n * 512 + k - 512];
  wcat2[idx] = f2bf(v);
}

// ---- m97-structure NT MFMA GEMM, split-K into per-z slice buffers ---------
// Cslice[z][m,n] = sum_{k in chunk z} A[m,k]*Bt[n,k]; plain f32 stores,
// deterministic (no atomics). Staging via global_load_lds width=16,
// linear LDS pitch 64 (no pad: gload_lds needs contiguous lane order).
template<int BM, int BN, int WROWS, int WCOLS>
__global__ __launch_bounds__(256, 2) void gemm_nt(
    const ushort* __restrict__ A, int lda,
    const ushort* __restrict__ B, int ldb,
    int Kchunk, float* __restrict__ Cout, int ldc, size_t cstride)
{
  constexpr int WTM = BM / WROWS;
  constexpr int WTN = BN / WCOLS;
  constexpr int MT = WTM / 16;
  constexpr int NT = WTN / 16;
  constexpr int AL = BM / 32;     // global_load_lds insts per wave for A tile
  constexpr int BL = BN / 32;

  __shared__ __align__(16) ushort As[BM * 64];
  __shared__ __align__(16) ushort Bs[BN * 64];

  const int t = threadIdx.x;
  const int wave = t >> 6;
  const int lane = t & 63;
  const int q = lane >> 4;
  const int ln = lane & 15;
  const int wr = wave / WCOLS;
  const int wc = wave % WCOLS;
  const int mbase = wr * WTM;
  const int nbase = wc * WTN;

  const int n0 = blockIdx.x * BN;
  const int m0 = blockIdx.y * BM;
  const int kbase = blockIdx.z * Kchunk;
  float* __restrict__ Cs = Cout + (size_t)blockIdx.z * cstride;

  f32x4 acc[MT][NT];
#pragma unroll
  for (int i = 0; i < MT; i++)
#pragma unroll
    for (int j = 0; j < NT; j++)
#pragma unroll
      for (int r = 0; r < 4; r++) acc[i][j][r] = 0.f;

  for (int kt = 0; kt < Kchunk; kt += 64) {
    const int kg = kbase + kt;
#pragma unroll
    for (int i = 0; i < AL; i++) {
      const int g = (wave * AL + i) * 64 + lane;   // 16B chunk idx; linear in lane
      const int row = g >> 3, c8 = g & 7;          // 8 chunks per 64-col row
      gload16(A + (size_t)(m0 + row) * lda + kg + c8 * 8, &As[g * 8]);
    }
#pragma unroll
    for (int i = 0; i < BL; i++) {
      const int g = (wave * BL + i) * 64 + lane;
      const int row = g >> 3, c8 = g & 7;
      gload16(B + (size_t)(n0 + row) * ldb + kg + c8 * 8, &Bs[g * 8]);
    }
    __syncthreads();   // compiler emits vmcnt(0) drain here -> LDS valid
#pragma unroll
    for (int kk = 0; kk < 64; kk += 32) {
      bf16x8 af[MT], bfr[NT];
#pragma unroll
      for (int i = 0; i < MT; i++)
        af[i] = *(const bf16x8*)(&As[(mbase + i * 16 + ln) * 64 + kk + q * 8]);
#pragma unroll
      for (int j = 0; j < NT; j++)
        bfr[j] = *(const bf16x8*)(&Bs[(nbase + j * 16 + ln) * 64 + kk + q * 8]);
#pragma unroll
      for (int i = 0; i < MT; i++)
#pragma unroll
        for (int j = 0; j < NT; j++)
          acc[i][j] = __builtin_amdgcn_mfma_f32_16x16x32_bf16(af[i], bfr[j], acc[i][j], 0, 0, 0);
    }
    __syncthreads();
  }

#pragma unroll
  for (int i = 0; i < MT; i++)
#pragma unroll
    for (int j = 0; j < NT; j++)
#pragma unroll
      for (int r = 0; r < 4; r++) {
        const int m = m0 + mbase + i * 16 + q * 4 + r;   // C/D: row=(lane>>4)*4+reg
        const int n = n0 + nbase + j * 16 + ln;          //      col=lane&15
        Cs[(size_t)m * ldc + n] = acc[i][j][r];
      }
}

// ---- red_agg1: agg1[m][c] = sum_z slices[z][m][c] (float4 units) ----------
__global__ __launch_bounds__(256) void red_agg1(const float* __restrict__ sl,
                                                float* __restrict__ agg1) {
  const int idx = blockIdx.x * 256 + threadIdx.x;   // 4096*32/4 = 32768
  f32x4 s = {0.f, 0.f, 0.f, 0.f};
#pragma unroll
  for (int z = 0; z < 16; z++) {
    f32x4 v = *(const f32x4*)(sl + (size_t)z * N_ATOMS * FDIM + (size_t)idx * 4);
    s += v;
  }
  *(f32x4*)(agg1 + (size_t)idx * 4) = s;
}

// ---- epi_agg2: cat2[m][512+n] = bf16(sum_z sl[z][m][n] * rdeg[m]) ---------
__global__ __launch_bounds__(256) void epi_agg2(const float* __restrict__ sl,
                                                const float* __restrict__ rdeg,
                                                ushort* __restrict__ cat2) {
  const int idx = blockIdx.x * 256 + threadIdx.x;   // 4096*128 float4 units
  const int m = idx >> 7;
  const int n4 = (idx & 127) * 4;
  f32x4 s = {0.f, 0.f, 0.f, 0.f};
#pragma unroll
  for (int z = 0; z < 4; z++) {
    f32x4 v = *(const f32x4*)(sl + (size_t)z * N_ATOMS * HID + (size_t)m * HID + n4);
    s += v;
  }
  const float r = rdeg[m];
  ushort4 o;
  o.x = f2bf(s[0] * r); o.y = f2bf(s[1] * r);
  o.z = f2bf(s[2] * r); o.w = f2bf(s[3] * r);
  *(ushort4*)(cat2 + (size_t)m * 1024 + 512 + n4) = o;
}

// ---- epi_h2: h2f[m][n] = relu(sum_z sl[z][m][n] + bs2[n] + bn2[n]) --------
__global__ __launch_bounds__(256) void epi_h2(const float* __restrict__ sl,
                                              const float* __restrict__ bs2,
                                              const float* __restrict__ bn2,
                                              float* __restrict__ h2f) {
  const int idx = blockIdx.x * 256 + threadIdx.x;   // 4096*128 float4 units
  const int m = idx >> 7;
  const int n4 = (idx & 127) * 4;
  f32x4 s = {0.f, 0.f, 0.f, 0.f};
#pragma unroll
  for (int z = 0; z < 4; z++) {
    f32x4 v = *(const f32x4*)(sl + (size_t)z * N_ATOMS * HID + (size_t)m * HID + n4);
    s += v;
  }
  float4 b0 = *(const float4*)(bs2 + n4);
  float4 b1 = *(const float4*)(bn2 + n4);
  f32x4 o;
  o[0] = fmaxf(s[0] + b0.x + b1.x, 0.f);
  o[1] = fmaxf(s[1] + b0.y + b1.y, 0.f);
  o[2] = fmaxf(s[2] + b0.z + b1.z, 0.f);
  o[3] = fmaxf(s[3] + b0.w + b1.w, 0.f);
  *(f32x4*)(h2f + (size_t)m * HID + n4) = o;
}

// ---- h1 = relu(x Ws1^T + (agg1*rdeg) Wn1^T + b) (all f32 in, bf16 out) ----
__global__ __launch_bounds__(256) void h1_kernel(
    const float* __restrict__ x, const float* __restrict__ agg1,
    const float* __restrict__ rdeg,
    const float* __restrict__ ws1, const float* __restrict__ bs1,
    const float* __restrict__ wn1, const float* __restrict__ bn1,
    ushort* __restrict__ cat2, ushort* __restrict__ h1t)
{
  const int idx = blockIdx.x * 256 + threadIdx.x;   // 4096*512
  const int m = idx >> 9;
  const int n = idx & 511;
  const float* xr = x + (size_t)m * FDIM;
  const float* ar = agg1 + (size_t)m * FDIM;
  const float* w1 = ws1 + (size_t)n * FDIM;
  const float* w2 = wn1 + (size_t)n * FDIM;
  float accs = 0.f, accn = 0.f;
#pragma unroll
  for (int k = 0; k < FDIM; k += 4) {
    float4 xv = *(const float4*)(xr + k);
    float4 av = *(const float4*)(ar + k);
    float4 wv = *(const float4*)(w1 + k);
    float4 nv = *(const float4*)(w2 + k);
    accs += xv.x * wv.x + xv.y * wv.y + xv.z * wv.z + xv.w * wv.w;
    accn += av.x * nv.x + av.y * nv.y + av.z * nv.z + av.w * nv.w;
  }
  float v = fmaxf(accs + accn * rdeg[m] + bs1[n] + bn1[n], 0.f);
  ushort h = f2bf(v);
  cat2[(size_t)m * 1024 + n] = h;
  h1t[(size_t)n * N_ATOMS + m] = h;
}

// ---- heads: atom logits + bond a/b vectors (h2f pre-activated f32) --------
// a_buf gets b_bond folded in; b_buf plain.
__global__ __launch_bounds__(256) void heads_kernel(
    const float* __restrict__ h2f,
    const float* __restrict__ w_atom, const float* __restrict__ b_atom,
    const float* __restrict__ w_bond, const float* __restrict__ b_bond,
    float* __restrict__ atom_out,
    float* __restrict__ a_buf, float* __restrict__ b_buf)
{
  const int idx = blockIdx.x * 256 + threadIdx.x;
  if (idx >= N_ATOMS * 40) return;
  const int m = idx / 40;
  const int c = idx - m * 40;
  const float* hr = h2f + (size_t)m * HID;
  const float* wr;
  if (c < 32)      wr = w_atom + (size_t)c * HID;
  else if (c < 36) wr = w_bond + (size_t)(c - 32) * 1024;        // a: W[:, :H]
  else             wr = w_bond + (size_t)(c - 36) * 1024 + 512;  // b: W[:, H:]
  float acc = 0.f;
#pragma unroll 4
  for (int k = 0; k < HID; k += 4) {
    float4 hv = *(const float4*)(hr + k);
    float4 w0 = *(const float4*)(wr + k);
    acc += hv.x * w0.x + hv.y * w0.y + hv.z * w0.z + hv.w * w0.w;
  }
  if (c < 32)      atom_out[(size_t)m * 32 + c] = acc + b_atom[c];
  else if (c < 36) a_buf[(size_t)m * 4 + (c - 32)] = acc + b_bond[c - 32];
  else             b_buf[(size_t)m * 4 + (c - 36)] = acc;
}

// ---- bond fill: out[i][j][0:4] (f32), diagonal explicitly zeroed ----------
// a_buf already contains b_bond; logits(i<j) = a[i] + b[j].
__global__ __launch_bounds__(256) void bond_fill(
    const float* __restrict__ av, const float* __restrict__ bv,
    float* __restrict__ out)
{
  const int idx = blockIdx.x * 256 + threadIdx.x;  // 4096*4096
  const int i = idx >> 12;
  const int j = idx & 4095;
  float4 r;
  if (i < j) {
    float4 ai = *(const float4*)(av + (size_t)i * 4);
    float4 bj = *(const float4*)(bv + (size_t)j * 4);
    r.x = ai.x + bj.x; r.y = ai.y + bj.y;
    r.z = ai.z + bj.z; r.w = ai.w + bj.w;
  } else if (i > j) {
    float4 aj = *(const float4*)(av + (size_t)j * 4);
    float4 bi = *(const float4*)(bv + (size_t)i * 4);
    r.x = aj.x + bi.x; r.y = aj.y + bi.y;
    r.z = aj.z + bi.z; r.w = aj.w + bi.w;
  } else {
    r.x = r.y = r.z = r.w = 0.f;   // diagonal stays zero (d_out is poisoned!)
  }
  *(float4*)(out + (size_t)idx * 4) = r;
}

extern "C" void kernel_launch(void* const* d_in, const int* in_sizes, int n_in,
                              void* d_out, int out_size, void* d_ws, size_t ws_size,
                              hipStream_t stream)
{
  const float* x        = (const float*)d_in[0];
  const float* adj      = (const float*)d_in[1];
  const float* w_self1  = (const float*)d_in[2];
  const float* b_self1  = (const float*)d_in[3];
  const float* w_neigh1 = (const float*)d_in[4];
  const float* b_neigh1 = (const float*)d_in[5];
  const float* w_self2  = (const float*)d_in[6];
  const float* b_self2  = (const float*)d_in[7];
  const float* w_neigh2 = (const float*)d_in[8];
  const float* b_neigh2 = (const float*)d_in[9];
  const float* w_atom   = (const float*)d_in[10];
  const float* b_atom   = (const float*)d_in[11];
  const float* w_bond   = (const float*)d_in[12];
  const float* b_bond   = (const float*)d_in[13];

  char* w = (char*)d_ws;
  float*  rdeg  = (float*)w;  w += (size_t)N_ATOMS * sizeof(float);
  float*  agg1  = (float*)w;  w += (size_t)N_ATOMS * FDIM * sizeof(float);
  float*  a_buf = (float*)w;  w += (size_t)N_ATOMS * 4 * sizeof(float);
  float*  b_buf = (float*)w;  w += (size_t)N_ATOMS * 4 * sizeof(float);
  ushort* adjb  = (ushort*)w; w += (size_t)N_ATOMS * N_ATOMS * sizeof(ushort);
  ushort* xt    = (ushort*)w; w += (size_t)FDIM * N_ATOMS * sizeof(ushort);
  ushort* h1t   = (ushort*)w; w += (size_t)HID * N_ATOMS * sizeof(ushort);
  ushort* cat2  = (ushort*)w; w += (size_t)N_ATOMS * 1024 * sizeof(ushort);
  ushort* wcat2 = (ushort*)w; w += (size_t)HID * 1024 * sizeof(ushort);
  float*  h2f   = (float*)w;  w += (size_t)N_ATOMS * HID * sizeof(float);
  float*  sl    = (float*)w;  w += (size_t)4 * N_ATOMS * HID * sizeof(float);
  // sl (32 MB) is reused: agg1 slices (16 x 4096 x 32 = 8 MB), then agg2
  // slices (4 x 4096 x 512), then h2 slices (4 x 4096 x 512).

  float* atom_out = (float*)d_out;
  float* bond_out = (float*)d_out + (size_t)N_ATOMS * FDIM;

  prep_adj<<<N_ATOMS, 256, 0, stream>>>(adj, adjb, rdeg);
  prep_x<<<(N_ATOMS * FDIM) / 256, 256, 0, stream>>>(x, xt);
  prep_w2<<<(HID * 1024) / 256, 256, 0, stream>>>(w_self2, w_neigh2, wcat2);

  // agg1 slices: M=4096 N=32 K=4096, split-K=16 -> 512 blocks (2/CU)
  gemm_nt<128, 32, 4, 1><<<dim3(1, 32, 16), 256, 0, stream>>>(
      adjb, N_ATOMS, xt, N_ATOMS, 256, sl, FDIM, (size_t)N_ATOMS * FDIM);
  red_agg1<<<(N_ATOMS * FDIM / 4) / 256, 256, 0, stream>>>(sl, agg1);
  h1_kernel<<<(N_ATOMS * HID) / 256, 256, 0, stream>>>(
      x, agg1, rdeg, w_self1, b_self1, w_neigh1, b_neigh1, cat2, h1t);
  // agg2 slices: M=4096 N=512 K=4096, split-K=4 -> 512 blocks (2/CU)
  gemm_nt<128, 128, 2, 2><<<dim3(4, 32, 4), 256, 0, stream>>>(
      adjb, N_ATOMS, h1t, N_ATOMS, 1024, sl, HID, (size_t)N_ATOMS * HID);
  epi_agg2<<<(N_ATOMS * HID / 4) / 256, 256, 0, stream>>>(sl, rdeg, cat2);
  // h2 slices: M=4096 N=512 K=1024, split-K=4 -> 512 blocks (2/CU)
  gemm_nt<128, 128, 2, 2><<<dim3(4, 32, 4), 256, 0, stream>>>(
      cat2, 1024, wcat2, 1024, 256, sl, HID, (size_t)N_ATOMS * HID);
  epi_h2<<<(N_ATOMS * HID / 4) / 256, 256, 0, stream>>>(sl, b_self2, b_neigh2, h2f);
  heads_kernel<<<(N_ATOMS * 40 + 255) / 256, 256, 0, stream>>>(
      h2f, w_atom, b_atom, w_bond, b_bond, atom_out, a_buf, b_buf);
  bond_fill<<<(N_ATOMS * N_ATOMS) / 256, 256, 0, stream>>>(a_buf, b_buf, bond_out);
}

// Round 3
// 552.475 us; speedup vs baseline: 1.0737x; 1.0092x over previous
//
#include <hip/hip_runtime.h>

#define N_ATOMS 4096
#define FDIM 32
#define HID 512

typedef __bf16 bf16x8 __attribute__((ext_vector_type(8)));
typedef float f32x4 __attribute__((ext_vector_type(4)));

__device__ __forceinline__ float bf2f(ushort h) {
  union { uint u; float f; } v; v.u = ((uint)h) << 16; return v.f;
}
__device__ __forceinline__ ushort f2bf(float f) {
  union { float f; uint u; } v; v.f = f;
  uint u = v.u;
  u += 0x7fffu + ((u >> 16) & 1u);   // RNE
  return (ushort)(u >> 16);
}

// async global->LDS, 16B per lane; LDS dest must be linear: base + lane*16
__device__ __forceinline__ void gload16(const ushort* g, ushort* l) {
  __builtin_amdgcn_global_load_lds(
      (const __attribute__((address_space(1))) void*)g,
      (__attribute__((address_space(3))) void*)l,
      16, 0, 0);
}

// ---- prep_adj: adjb = bf16(adj); rdeg[i] = 1/max(rowsum_f32, 1) -----------
__global__ __launch_bounds__(256) void prep_adj(const float* __restrict__ adj,
                                                ushort* __restrict__ adjb,
                                                float* __restrict__ rdeg) {
  const int row = blockIdx.x;
  const int t = threadIdx.x;
  const float* r = adj + (size_t)row * N_ATOMS;
  ushort* w = adjb + (size_t)row * N_ATOMS;
  float s = 0.f;
#pragma unroll
  for (int i = 0; i < 4; i++) {
    const int c = (t + i * 256) * 4;
    float4 v = *(const float4*)(r + c);
    s += v.x + v.y + v.z + v.w;
    ushort4 o;
    o.x = f2bf(v.x); o.y = f2bf(v.y); o.z = f2bf(v.z); o.w = f2bf(v.w);
    *(ushort4*)(w + c) = o;
  }
#pragma unroll
  for (int off = 32; off; off >>= 1) s += __shfl_down(s, off);
  __shared__ float red[4];
  if ((t & 63) == 0) red[t >> 6] = s;
  __syncthreads();
  if (t == 0) rdeg[row] = 1.f / fmaxf(red[0] + red[1] + red[2] + red[3], 1.f);
}

// ---- fused: xt[c][m] = bf16(x[m][c]) ; wcat2[n][0:512|512:1024] -----------
__global__ __launch_bounds__(256) void prep_misc(const float* __restrict__ x,
                                                 ushort* __restrict__ xt,
                                                 const float* __restrict__ ws2,
                                                 const float* __restrict__ wn2,
                                                 ushort* __restrict__ wcat2) {
  const int idx = blockIdx.x * 256 + threadIdx.x;   // 4096*32 + 512*1024
  if (idx < N_ATOMS * FDIM) {
    const int m = idx >> 5, c = idx & 31;
    xt[(size_t)c * N_ATOMS + m] = f2bf(x[(size_t)m * FDIM + c]);
  } else {
    const int j = idx - N_ATOMS * FDIM;
    const int n = j >> 10, k = j & 1023;
    float v = (k < 512) ? ws2[(size_t)n * 512 + k] : wn2[(size_t)n * 512 + k - 512];
    wcat2[j] = f2bf(v);
  }
}

// ---- m97-structure NT MFMA GEMM, split-K slices, XCD-chunked swizzle ------
// Launched 1-D with nwg = GX*32*GZ blocks (nwg % 8 == 0). Logical tile =
// swz(id) so each XCD gets a contiguous (x,y)-chunk -> A panel L2-resident.
// Cslice[z][m,n] = sum_{k in chunk z} A[m,k]*Bt[n,k]; plain f32 stores.
template<int BM, int BN, int WROWS, int WCOLS, int GX, int GZ>
__global__ __launch_bounds__(256, 2) void gemm_nt(
    const ushort* __restrict__ A, int lda,
    const ushort* __restrict__ B, int ldb,
    int Kchunk, float* __restrict__ Cout, int ldc, size_t cstride)
{
  constexpr int WTM = BM / WROWS;
  constexpr int WTN = BN / WCOLS;
  constexpr int MT = WTM / 16;
  constexpr int NT = WTN / 16;
  constexpr int AL = BM / 32;     // global_load_lds insts per wave for A tile
  constexpr int BL = BN / 32;
  constexpr int NWG = GX * 32 * GZ;

  __shared__ __align__(16) ushort As[BM * 64];
  __shared__ __align__(16) ushort Bs[BN * 64];

  const int id = blockIdx.x;
  const int swz = (id & 7) * (NWG / 8) + (id >> 3);   // T1: XCD-chunked (nwg%8==0)
  const int bx = swz % GX;
  const int by = (swz / GX) % 32;
  const int bz = swz / (GX * 32);

  const int t = threadIdx.x;
  const int wave = t >> 6;
  const int lane = t & 63;
  const int q = lane >> 4;
  const int ln = lane & 15;
  const int wr = wave / WCOLS;
  const int wc = wave % WCOLS;
  const int mbase = wr * WTM;
  const int nbase = wc * WTN;

  const int n0 = bx * BN;
  const int m0 = by * BM;
  const int kbase = bz * Kchunk;
  float* __restrict__ Cs = Cout + (size_t)bz * cstride;

  f32x4 acc[MT][NT];
#pragma unroll
  for (int i = 0; i < MT; i++)
#pragma unroll
    for (int j = 0; j < NT; j++)
#pragma unroll
      for (int r = 0; r < 4; r++) acc[i][j][r] = 0.f;

  for (int kt = 0; kt < Kchunk; kt += 64) {
    const int kg = kbase + kt;
#pragma unroll
    for (int i = 0; i < AL; i++) {
      const int g = (wave * AL + i) * 64 + lane;   // 16B chunk idx; linear in lane
      const int row = g >> 3, c8 = g & 7;          // 8 chunks per 64-col row
      gload16(A + (size_t)(m0 + row) * lda + kg + c8 * 8, &As[g * 8]);
    }
#pragma unroll
    for (int i = 0; i < BL; i++) {
      const int g = (wave * BL + i) * 64 + lane;
      const int row = g >> 3, c8 = g & 7;
      gload16(B + (size_t)(n0 + row) * ldb + kg + c8 * 8, &Bs[g * 8]);
    }
    __syncthreads();   // compiler emits vmcnt(0) drain here -> LDS valid
#pragma unroll
    for (int kk = 0; kk < 64; kk += 32) {
      bf16x8 af[MT], bfr[NT];
#pragma unroll
      for (int i = 0; i < MT; i++)
        af[i] = *(const bf16x8*)(&As[(mbase + i * 16 + ln) * 64 + kk + q * 8]);
#pragma unroll
      for (int j = 0; j < NT; j++)
        bfr[j] = *(const bf16x8*)(&Bs[(nbase + j * 16 + ln) * 64 + kk + q * 8]);
#pragma unroll
      for (int i = 0; i < MT; i++)
#pragma unroll
        for (int j = 0; j < NT; j++)
          acc[i][j] = __builtin_amdgcn_mfma_f32_16x16x32_bf16(af[i], bfr[j], acc[i][j], 0, 0, 0);
    }
    __syncthreads();
  }

#pragma unroll
  for (int i = 0; i < MT; i++)
#pragma unroll
    for (int j = 0; j < NT; j++)
#pragma unroll
      for (int r = 0; r < 4; r++) {
        const int m = m0 + mbase + i * 16 + q * 4 + r;   // C/D: row=(lane>>4)*4+reg
        const int n = n0 + nbase + j * 16 + ln;          //      col=lane&15
        Cs[(size_t)m * ldc + n] = acc[i][j][r];
      }
}

// ---- red_agg1: agg1[m][c] = sum_z slices[z][m][c] (float4 units) ----------
__global__ __launch_bounds__(256) void red_agg1(const float* __restrict__ sl,
                                                float* __restrict__ agg1) {
  const int idx = blockIdx.x * 256 + threadIdx.x;   // 4096*32/4 = 32768
  f32x4 s = {0.f, 0.f, 0.f, 0.f};
#pragma unroll
  for (int z = 0; z < 16; z++) {
    f32x4 v = *(const f32x4*)(sl + (size_t)z * N_ATOMS * FDIM + (size_t)idx * 4);
    s += v;
  }
  *(f32x4*)(agg1 + (size_t)idx * 4) = s;
}

// ---- epi_agg2: cat2[m][512+n] = bf16(sum_z sl[z][m][n] * rdeg[m]) ---------
__global__ __launch_bounds__(256) void epi_agg2(const float* __restrict__ sl,
                                                const float* __restrict__ rdeg,
                                                ushort* __restrict__ cat2) {
  const int idx = blockIdx.x * 256 + threadIdx.x;   // 4096*128 float4 units
  const int m = idx >> 7;
  const int n4 = (idx & 127) * 4;
  f32x4 s = {0.f, 0.f, 0.f, 0.f};
#pragma unroll
  for (int z = 0; z < 4; z++) {
    f32x4 v = *(const f32x4*)(sl + (size_t)z * N_ATOMS * HID + (size_t)m * HID + n4);
    s += v;
  }
  const float r = rdeg[m];
  ushort4 o;
  o.x = f2bf(s[0] * r); o.y = f2bf(s[1] * r);
  o.z = f2bf(s[2] * r); o.w = f2bf(s[3] * r);
  *(ushort4*)(cat2 + (size_t)m * 1024 + 512 + n4) = o;
}

// ---- epi_h2: h2f[m][n] = relu(sum_z sl[z][m][n] + bs2[n] + bn2[n]) --------
__global__ __launch_bounds__(256) void epi_h2(const float* __restrict__ sl,
                                              const float* __restrict__ bs2,
                                              const float* __restrict__ bn2,
                                              float* __restrict__ h2f) {
  const int idx = blockIdx.x * 256 + threadIdx.x;   // 4096*128 float4 units
  const int m = idx >> 7;
  const int n4 = (idx & 127) * 4;
  f32x4 s = {0.f, 0.f, 0.f, 0.f};
#pragma unroll
  for (int z = 0; z < 2; z++) {
    f32x4 v = *(const f32x4*)(sl + (size_t)z * N_ATOMS * HID + (size_t)m * HID + n4);
    s += v;
  }
  float4 b0 = *(const float4*)(bs2 + n4);
  float4 b1 = *(const float4*)(bn2 + n4);
  f32x4 o;
  o[0] = fmaxf(s[0] + b0.x + b1.x, 0.f);
  o[1] = fmaxf(s[1] + b0.y + b1.y, 0.f);
  o[2] = fmaxf(s[2] + b0.z + b1.z, 0.f);
  o[3] = fmaxf(s[3] + b0.w + b1.w, 0.f);
  *(f32x4*)(h2f + (size_t)m * HID + n4) = o;
}

// ---- h1 = relu(x Ws1^T + (agg1*rdeg) Wn1^T + b) (all f32 in, bf16 out) ----
__global__ __launch_bounds__(256) void h1_kernel(
    const float* __restrict__ x, const float* __restrict__ agg1,
    const float* __restrict__ rdeg,
    const float* __restrict__ ws1, const float* __restrict__ bs1,
    const float* __restrict__ wn1, const float* __restrict__ bn1,
    ushort* __restrict__ cat2, ushort* __restrict__ h1t)
{
  const int idx = blockIdx.x * 256 + threadIdx.x;   // 4096*512
  const int m = idx >> 9;
  const int n = idx & 511;
  const float* xr = x + (size_t)m * FDIM;
  const float* ar = agg1 + (size_t)m * FDIM;
  const float* w1 = ws1 + (size_t)n * FDIM;
  const float* w2 = wn1 + (size_t)n * FDIM;
  float accs = 0.f, accn = 0.f;
#pragma unroll
  for (int k = 0; k < FDIM; k += 4) {
    float4 xv = *(const float4*)(xr + k);
    float4 av = *(const float4*)(ar + k);
    float4 wv = *(const float4*)(w1 + k);
    float4 nv = *(const float4*)(w2 + k);
    accs += xv.x * wv.x + xv.y * wv.y + xv.z * wv.z + xv.w * wv.w;
    accn += av.x * nv.x + av.y * nv.y + av.z * nv.z + av.w * nv.w;
  }
  float v = fmaxf(accs + accn * rdeg[m] + bs1[n] + bn1[n], 0.f);
  ushort h = f2bf(v);
  cat2[(size_t)m * 1024 + n] = h;
  h1t[(size_t)n * N_ATOMS + m] = h;
}

// ---- heads: atom logits + bond a/b vectors (h2f pre-activated f32) --------
__global__ __launch_bounds__(256) void heads_kernel(
    const float* __restrict__ h2f,
    const float* __restrict__ w_atom, const float* __restrict__ b_atom,
    const float* __restrict__ w_bond, const float* __restrict__ b_bond,
    float* __restrict__ atom_out,
    float* __restrict__ a_buf, float* __restrict__ b_buf)
{
  const int idx = blockIdx.x * 256 + threadIdx.x;
  if (idx >= N_ATOMS * 40) return;
  const int m = idx / 40;
  const int c = idx - m * 40;
  const float* hr = h2f + (size_t)m * HID;
  const float* wr;
  if (c < 32)      wr = w_atom + (size_t)c * HID;
  else if (c < 36) wr = w_bond + (size_t)(c - 32) * 1024;        // a: W[:, :H]
  else             wr = w_bond + (size_t)(c - 36) * 1024 + 512;  // b: W[:, H:]
  float acc = 0.f;
#pragma unroll 4
  for (int k = 0; k < HID; k += 4) {
    float4 hv = *(const float4*)(hr + k);
    float4 w0 = *(const float4*)(wr + k);
    acc += hv.x * w0.x + hv.y * w0.y + hv.z * w0.z + hv.w * w0.w;
  }
  if (c < 32)      atom_out[(size_t)m * 32 + c] = acc + b_atom[c];
  else if (c < 36) a_buf[(size_t)m * 4 + (c - 32)] = acc + b_bond[c - 32];
  else             b_buf[(size_t)m * 4 + (c - 36)] = acc;
}

// ---- bond fill: out[i][j][0:4] (f32), diagonal explicitly zeroed ----------
__global__ __launch_bounds__(256) void bond_fill(
    const float* __restrict__ av, const float* __restrict__ bv,
    float* __restrict__ out)
{
  const int idx = blockIdx.x * 256 + threadIdx.x;  // 4096*4096
  const int i = idx >> 12;
  const int j = idx & 4095;
  float4 r;
  if (i < j) {
    float4 ai = *(const float4*)(av + (size_t)i * 4);
    float4 bj = *(const float4*)(bv + (size_t)j * 4);
    r.x = ai.x + bj.x; r.y = ai.y + bj.y;
    r.z = ai.z + bj.z; r.w = ai.w + bj.w;
  } else if (i > j) {
    float4 aj = *(const float4*)(av + (size_t)j * 4);
    float4 bi = *(const float4*)(bv + (size_t)i * 4);
    r.x = aj.x + bi.x; r.y = aj.y + bi.y;
    r.z = aj.z + bi.z; r.w = aj.w + bi.w;
  } else {
    r.x = r.y = r.z = r.w = 0.f;   // diagonal stays zero (d_out is poisoned!)
  }
  *(float4*)(out + (size_t)idx * 4) = r;
}

extern "C" void kernel_launch(void* const* d_in, const int* in_sizes, int n_in,
                              void* d_out, int out_size, void* d_ws, size_t ws_size,
                              hipStream_t stream)
{
  const float* x        = (const float*)d_in[0];
  const float* adj      = (const float*)d_in[1];
  const float* w_self1  = (const float*)d_in[2];
  const float* b_self1  = (const float*)d_in[3];
  const float* w_neigh1 = (const float*)d_in[4];
  const float* b_neigh1 = (const float*)d_in[5];
  const float* w_self2  = (const float*)d_in[6];
  const float* b_self2  = (const float*)d_in[7];
  const float* w_neigh2 = (const float*)d_in[8];
  const float* b_neigh2 = (const float*)d_in[9];
  const float* w_atom   = (const float*)d_in[10];
  const float* b_atom   = (const float*)d_in[11];
  const float* w_bond   = (const float*)d_in[12];
  const float* b_bond   = (const float*)d_in[13];

  char* w = (char*)d_ws;
  float*  rdeg  = (float*)w;  w += (size_t)N_ATOMS * sizeof(float);
  float*  agg1  = (float*)w;  w += (size_t)N_ATOMS * FDIM * sizeof(float);
  float*  a_buf = (float*)w;  w += (size_t)N_ATOMS * 4 * sizeof(float);
  float*  b_buf = (float*)w;  w += (size_t)N_ATOMS * 4 * sizeof(float);
  ushort* adjb  = (ushort*)w; w += (size_t)N_ATOMS * N_ATOMS * sizeof(ushort);
  ushort* xt    = (ushort*)w; w += (size_t)FDIM * N_ATOMS * sizeof(ushort);
  ushort* h1t   = (ushort*)w; w += (size_t)HID * N_ATOMS * sizeof(ushort);
  ushort* cat2  = (ushort*)w; w += (size_t)N_ATOMS * 1024 * sizeof(ushort);
  ushort* wcat2 = (ushort*)w; w += (size_t)HID * 1024 * sizeof(ushort);
  float*  h2f   = (float*)w;  w += (size_t)N_ATOMS * HID * sizeof(float);
  float*  sl    = (float*)w;  w += (size_t)4 * N_ATOMS * HID * sizeof(float);
  // sl (32 MB) reused: agg1 slices (16 x 4096 x 32), agg2 slices (4 x 8 MB),
  // h2 slices (2 x 8 MB).

  float* atom_out = (float*)d_out;
  float* bond_out = (float*)d_out + (size_t)N_ATOMS * FDIM;

  prep_adj<<<N_ATOMS, 256, 0, stream>>>(adj, adjb, rdeg);
  prep_misc<<<(N_ATOMS * FDIM + HID * 1024) / 256, 256, 0, stream>>>(
      x, xt, w_self2, w_neigh2, wcat2);

  // agg1 slices: M=4096 N=32 K=4096, split-K=16 -> 512 blocks (2/CU)
  gemm_nt<128, 32, 4, 1, 1, 16><<<512, 256, 0, stream>>>(
      adjb, N_ATOMS, xt, N_ATOMS, 256, sl, FDIM, (size_t)N_ATOMS * FDIM);
  red_agg1<<<(N_ATOMS * FDIM / 4) / 256, 256, 0, stream>>>(sl, agg1);
  h1_kernel<<<(N_ATOMS * HID) / 256, 256, 0, stream>>>(
      x, agg1, rdeg, w_self1, b_self1, w_neigh1, b_neigh1, cat2, h1t);
  // agg2 slices: M=4096 N=512 K=4096, split-K=4 -> 512 blocks, XCD-chunked
  gemm_nt<128, 128, 2, 2, 4, 4><<<512, 256, 0, stream>>>(
      adjb, N_ATOMS, h1t, N_ATOMS, 1024, sl, HID, (size_t)N_ATOMS * HID);
  epi_agg2<<<(N_ATOMS * HID / 4) / 256, 256, 0, stream>>>(sl, rdeg, cat2);
  // h2 slices: M=4096 N=512 K=1024, BN=64, split-K=2 -> 512 blocks
  gemm_nt<128, 64, 2, 2, 8, 2><<<512, 256, 0, stream>>>(
      cat2, 1024, wcat2, 1024, 512, sl, HID, (size_t)N_ATOMS * HID);
  epi_h2<<<(N_ATOMS * HID / 4) / 256, 256, 0, stream>>>(sl, b_self2, b_neigh2, h2f);
  heads_kernel<<<(N_ATOMS * 40 + 255) / 256, 256, 0, stream>>>(
      h2f, w_atom, b_atom, w_bond, b_bond, atom_out, a_buf, b_buf);
  bond_fill<<<(N_ATOMS * N_ATOMS) / 256, 256, 0, stream>>>(a_buf, b_buf, bond_out);
}

// Round 4
// 510.980 us; speedup vs baseline: 1.1609x; 1.0812x over previous
//
#include <hip/hip_runtime.h>

#define N_ATOMS 4096
#define FDIM 32
#define HID 512

typedef __bf16 bf16x8 __attribute__((ext_vector_type(8)));
typedef float f32x4 __attribute__((ext_vector_type(4)));

__device__ __forceinline__ float bf2f(ushort h) {
  union { uint u; float f; } v; v.u = ((uint)h) << 16; return v.f;
}
__device__ __forceinline__ ushort f2bf(float f) {
  union { float f; uint u; } v; v.f = f;
  uint u = v.u;
  u += 0x7fffu + ((u >> 16) & 1u);   // RNE
  return (ushort)(u >> 16);
}

// async global->LDS, 16B per lane; LDS dest must be linear: base + lane*16
__device__ __forceinline__ void gload16(const ushort* g, ushort* l) {
  __builtin_amdgcn_global_load_lds(
      (const __attribute__((address_space(1))) void*)g,
      (__attribute__((address_space(3))) void*)l,
      16, 0, 0);
}

// ---- prep_adj: adjb = bf16(adj); rdeg[i] = 1/max(rowsum_f32, 1) -----------
__global__ __launch_bounds__(256) void prep_adj(const float* __restrict__ adj,
                                                ushort* __restrict__ adjb,
                                                float* __restrict__ rdeg) {
  const int row = blockIdx.x;
  const int t = threadIdx.x;
  const float* r = adj + (size_t)row * N_ATOMS;
  ushort* w = adjb + (size_t)row * N_ATOMS;
  float s = 0.f;
#pragma unroll
  for (int i = 0; i < 4; i++) {
    const int c = (t + i * 256) * 4;
    float4 v = *(const float4*)(r + c);
    s += v.x + v.y + v.z + v.w;
    ushort4 o;
    o.x = f2bf(v.x); o.y = f2bf(v.y); o.z = f2bf(v.z); o.w = f2bf(v.w);
    *(ushort4*)(w + c) = o;
  }
#pragma unroll
  for (int off = 32; off; off >>= 1) s += __shfl_down(s, off);
  __shared__ float red[4];
  if ((t & 63) == 0) red[t >> 6] = s;
  __syncthreads();
  if (t == 0) rdeg[row] = 1.f / fmaxf(red[0] + red[1] + red[2] + red[3], 1.f);
}

// ---- fused preps: xt (x^T bf16), wcat2, wb (heads weights bf16) -----------
// wb rows: 0-31 w_atom, 32-35 w_bond[:, :512], 36-39 w_bond[:, 512:], 40-63 zero
__global__ __launch_bounds__(256) void prep_misc(const float* __restrict__ x,
                                                 ushort* __restrict__ xt,
                                                 const float* __restrict__ ws2,
                                                 const float* __restrict__ wn2,
                                                 ushort* __restrict__ wcat2,
                                                 const float* __restrict__ w_atom,
                                                 const float* __restrict__ w_bond,
                                                 ushort* __restrict__ wb) {
  const int idx = blockIdx.x * 256 + threadIdx.x;  // 131072 + 524288 + 32768
  if (idx < N_ATOMS * FDIM) {
    const int m = idx >> 5, c = idx & 31;
    xt[(size_t)c * N_ATOMS + m] = f2bf(x[(size_t)m * FDIM + c]);
  } else if (idx < N_ATOMS * FDIM + HID * 1024) {
    const int j = idx - N_ATOMS * FDIM;
    const int n = j >> 10, k = j & 1023;
    float v = (k < 512) ? ws2[(size_t)n * 512 + k] : wn2[(size_t)n * 512 + k - 512];
    wcat2[j] = f2bf(v);
  } else {
    const int j = idx - N_ATOMS * FDIM - HID * 1024;   // 64*512
    const int r = j >> 9, k = j & 511;
    float v;
    if (r < 32)      v = w_atom[(size_t)r * HID + k];
    else if (r < 36) v = w_bond[(size_t)(r - 32) * 1024 + k];
    else if (r < 40) v = w_bond[(size_t)(r - 36) * 1024 + 512 + k];
    else             v = 0.f;
    wb[j] = f2bf(v);
  }
}

// ---- m97-structure NT MFMA GEMM ------------------------------------------
// MODE 0: split-K slice store (f32), Cs = Cout + bz*cstride
// MODE 3: heads epilogue: n<32 atom_out(+b_atom); 32-35 a_buf(+b_bond);
//         36-39 b_buf; n>=40 discard. (GX must be 1, GZ 1.)
template<int BM, int BN, int WROWS, int WCOLS, int GX, int GZ, int MODE>
__global__ __launch_bounds__(256, 2) void gemm_nt(
    const ushort* __restrict__ A, int lda,
    const ushort* __restrict__ B, int ldb,
    int Kchunk, float* __restrict__ Cout, int ldc, size_t cstride,
    const float* __restrict__ e0, const float* __restrict__ e1,
    float* __restrict__ o0, float* __restrict__ o1, float* __restrict__ o2)
{
  constexpr int WTM = BM / WROWS;
  constexpr int WTN = BN / WCOLS;
  constexpr int MT = WTM / 16;
  constexpr int NT = WTN / 16;
  constexpr int AL = BM / 32;     // global_load_lds insts per wave for A tile
  constexpr int BL = BN / 32;
  constexpr int NWG = GX * 32 * GZ;

  __shared__ __align__(16) ushort As[BM * 64];
  __shared__ __align__(16) ushort Bs[BN * 64];

  const int id = blockIdx.x;
  const int swz = (id & 7) * (NWG / 8) + (id >> 3);   // XCD-chunked (nwg%8==0)
  const int bx = swz % GX;
  const int by = (swz / GX) % 32;
  const int bz = swz / (GX * 32);

  const int t = threadIdx.x;
  const int wave = t >> 6;
  const int lane = t & 63;
  const int q = lane >> 4;
  const int ln = lane & 15;
  const int wr = wave / WCOLS;
  const int wc = wave % WCOLS;
  const int mbase = wr * WTM;
  const int nbase = wc * WTN;

  const int n0 = bx * BN;
  const int m0 = by * BM;
  const int kbase = bz * Kchunk;
  float* __restrict__ Cs = Cout + (size_t)bz * cstride;

  f32x4 acc[MT][NT];
#pragma unroll
  for (int i = 0; i < MT; i++)
#pragma unroll
    for (int j = 0; j < NT; j++)
#pragma unroll
      for (int r = 0; r < 4; r++) acc[i][j][r] = 0.f;

  for (int kt = 0; kt < Kchunk; kt += 64) {
    const int kg = kbase + kt;
#pragma unroll
    for (int i = 0; i < AL; i++) {
      const int g = (wave * AL + i) * 64 + lane;   // 16B chunk idx; linear in lane
      const int row = g >> 3, c8 = g & 7;          // 8 chunks per 64-col row
      gload16(A + (size_t)(m0 + row) * lda + kg + c8 * 8, &As[g * 8]);
    }
#pragma unroll
    for (int i = 0; i < BL; i++) {
      const int g = (wave * BL + i) * 64 + lane;
      const int row = g >> 3, c8 = g & 7;
      gload16(B + (size_t)(n0 + row) * ldb + kg + c8 * 8, &Bs[g * 8]);
    }
    __syncthreads();   // compiler emits vmcnt(0) drain here -> LDS valid
#pragma unroll
    for (int kk = 0; kk < 64; kk += 32) {
      bf16x8 af[MT], bfr[NT];
#pragma unroll
      for (int i = 0; i < MT; i++)
        af[i] = *(const bf16x8*)(&As[(mbase + i * 16 + ln) * 64 + kk + q * 8]);
#pragma unroll
      for (int j = 0; j < NT; j++)
        bfr[j] = *(const bf16x8*)(&Bs[(nbase + j * 16 + ln) * 64 + kk + q * 8]);
#pragma unroll
      for (int i = 0; i < MT; i++)
#pragma unroll
        for (int j = 0; j < NT; j++)
          acc[i][j] = __builtin_amdgcn_mfma_f32_16x16x32_bf16(af[i], bfr[j], acc[i][j], 0, 0, 0);
    }
    __syncthreads();
  }

#pragma unroll
  for (int i = 0; i < MT; i++)
#pragma unroll
    for (int j = 0; j < NT; j++)
#pragma unroll
      for (int r = 0; r < 4; r++) {
        const int m = m0 + mbase + i * 16 + q * 4 + r;   // C/D: row=(lane>>4)*4+reg
        const int n = n0 + nbase + j * 16 + ln;          //      col=lane&15
        const float v = acc[i][j][r];
        if (MODE == 0) {
          Cs[(size_t)m * ldc + n] = v;
        } else {
          if (n < 32)      o0[(size_t)m * 32 + n] = v + e0[n];
          else if (n < 36) o1[(size_t)m * 4 + (n - 32)] = v + e1[n - 32];
          else if (n < 40) o2[(size_t)m * 4 + (n - 36)] = v;
        }
      }
}

// ---- red_agg1: agg1[m][c] = sum_z slices[z][m][c] (float4 units) ----------
__global__ __launch_bounds__(256) void red_agg1(const float* __restrict__ sl,
                                                float* __restrict__ agg1) {
  const int idx = blockIdx.x * 256 + threadIdx.x;   // 4096*32/4 = 32768
  f32x4 s = {0.f, 0.f, 0.f, 0.f};
#pragma unroll
  for (int z = 0; z < 16; z++) {
    f32x4 v = *(const f32x4*)(sl + (size_t)z * N_ATOMS * FDIM + (size_t)idx * 4);
    s += v;
  }
  *(f32x4*)(agg1 + (size_t)idx * 4) = s;
}

// ---- epi_agg2: cat2[m][512+n] = bf16(sum_z sl[z][m][n] * rdeg[m]) ---------
__global__ __launch_bounds__(256) void epi_agg2(const float* __restrict__ sl,
                                                const float* __restrict__ rdeg,
                                                ushort* __restrict__ cat2) {
  const int idx = blockIdx.x * 256 + threadIdx.x;   // 4096*128 float4 units
  const int m = idx >> 7;
  const int n4 = (idx & 127) * 4;
  f32x4 s = {0.f, 0.f, 0.f, 0.f};
#pragma unroll
  for (int z = 0; z < 4; z++) {
    f32x4 v = *(const f32x4*)(sl + (size_t)z * N_ATOMS * HID + (size_t)m * HID + n4);
    s += v;
  }
  const float r = rdeg[m];
  ushort4 o;
  o.x = f2bf(s[0] * r); o.y = f2bf(s[1] * r);
  o.z = f2bf(s[2] * r); o.w = f2bf(s[3] * r);
  *(ushort4*)(cat2 + (size_t)m * 1024 + 512 + n4) = o;
}

// ---- epi_h2: h2b[m][n] = bf16(relu(sum_z sl[z][m][n] + bs2[n] + bn2[n])) --
__global__ __launch_bounds__(256) void epi_h2(const float* __restrict__ sl,
                                              const float* __restrict__ bs2,
                                              const float* __restrict__ bn2,
                                              ushort* __restrict__ h2b) {
  const int idx = blockIdx.x * 256 + threadIdx.x;   // 4096*128 float4 units
  const int m = idx >> 7;
  const int n4 = (idx & 127) * 4;
  f32x4 s = {0.f, 0.f, 0.f, 0.f};
#pragma unroll
  for (int z = 0; z < 2; z++) {
    f32x4 v = *(const f32x4*)(sl + (size_t)z * N_ATOMS * HID + (size_t)m * HID + n4);
    s += v;
  }
  float4 b0 = *(const float4*)(bs2 + n4);
  float4 b1 = *(const float4*)(bn2 + n4);
  ushort4 o;
  o.x = f2bf(fmaxf(s[0] + b0.x + b1.x, 0.f));
  o.y = f2bf(fmaxf(s[1] + b0.y + b1.y, 0.f));
  o.z = f2bf(fmaxf(s[2] + b0.z + b1.z, 0.f));
  o.w = f2bf(fmaxf(s[3] + b0.w + b1.w, 0.f));
  *(ushort4*)(h2b + (size_t)m * HID + n4) = o;
}

// ---- h1 = relu(x Ws1^T + (agg1*rdeg) Wn1^T + b) (all f32 in, bf16 out) ----
__global__ __launch_bounds__(256) void h1_kernel(
    const float* __restrict__ x, const float* __restrict__ agg1,
    const float* __restrict__ rdeg,
    const float* __restrict__ ws1, const float* __restrict__ bs1,
    const float* __restrict__ wn1, const float* __restrict__ bn1,
    ushort* __restrict__ cat2, ushort* __restrict__ h1t)
{
  const int idx = blockIdx.x * 256 + threadIdx.x;   // 4096*512
  const int m = idx >> 9;
  const int n = idx & 511;
  const float* xr = x + (size_t)m * FDIM;
  const float* ar = agg1 + (size_t)m * FDIM;
  const float* w1 = ws1 + (size_t)n * FDIM;
  const float* w2 = wn1 + (size_t)n * FDIM;
  float accs = 0.f, accn = 0.f;
#pragma unroll
  for (int k = 0; k < FDIM; k += 4) {
    float4 xv = *(const float4*)(xr + k);
    float4 av = *(const float4*)(ar + k);
    float4 wv = *(const float4*)(w1 + k);
    float4 nv = *(const float4*)(w2 + k);
    accs += xv.x * wv.x + xv.y * wv.y + xv.z * wv.z + xv.w * wv.w;
    accn += av.x * nv.x + av.y * nv.y + av.z * nv.z + av.w * nv.w;
  }
  float v = fmaxf(accs + accn * rdeg[m] + bs1[n] + bn1[n], 0.f);
  ushort h = f2bf(v);
  cat2[(size_t)m * 1024 + n] = h;
  h1t[(size_t)n * N_ATOMS + m] = h;
}

// ---- bond fill: out[i][j][0:4] (f32), diagonal explicitly zeroed ----------
// a_buf already contains b_bond; logits(i<j) = a[i] + b[j].
__global__ __launch_bounds__(256) void bond_fill(
    const float* __restrict__ av, const float* __restrict__ bv,
    float* __restrict__ out)
{
  const int idx = blockIdx.x * 256 + threadIdx.x;  // 4096*4096
  const int i = idx >> 12;
  const int j = idx & 4095;
  float4 r;
  if (i < j) {
    float4 ai = *(const float4*)(av + (size_t)i * 4);
    float4 bj = *(const float4*)(bv + (size_t)j * 4);
    r.x = ai.x + bj.x; r.y = ai.y + bj.y;
    r.z = ai.z + bj.z; r.w = ai.w + bj.w;
  } else if (i > j) {
    float4 aj = *(const float4*)(av + (size_t)j * 4);
    float4 bi = *(const float4*)(bv + (size_t)i * 4);
    r.x = aj.x + bi.x; r.y = aj.y + bi.y;
    r.z = aj.z + bi.z; r.w = aj.w + bi.w;
  } else {
    r.x = r.y = r.z = r.w = 0.f;   // diagonal stays zero (d_out is poisoned!)
  }
  *(float4*)(out + (size_t)idx * 4) = r;
}

extern "C" void kernel_launch(void* const* d_in, const int* in_sizes, int n_in,
                              void* d_out, int out_size, void* d_ws, size_t ws_size,
                              hipStream_t stream)
{
  const float* x        = (const float*)d_in[0];
  const float* adj      = (const float*)d_in[1];
  const float* w_self1  = (const float*)d_in[2];
  const float* b_self1  = (const float*)d_in[3];
  const float* w_neigh1 = (const float*)d_in[4];
  const float* b_neigh1 = (const float*)d_in[5];
  const float* w_self2  = (const float*)d_in[6];
  const float* b_self2  = (const float*)d_in[7];
  const float* w_neigh2 = (const float*)d_in[8];
  const float* b_neigh2 = (const float*)d_in[9];
  const float* w_atom   = (const float*)d_in[10];
  const float* b_atom   = (const float*)d_in[11];
  const float* w_bond   = (const float*)d_in[12];
  const float* b_bond   = (const float*)d_in[13];

  char* w = (char*)d_ws;
  float*  rdeg  = (float*)w;  w += (size_t)N_ATOMS * sizeof(float);
  float*  agg1  = (float*)w;  w += (size_t)N_ATOMS * FDIM * sizeof(float);
  float*  a_buf = (float*)w;  w += (size_t)N_ATOMS * 4 * sizeof(float);
  float*  b_buf = (float*)w;  w += (size_t)N_ATOMS * 4 * sizeof(float);
  ushort* adjb  = (ushort*)w; w += (size_t)N_ATOMS * N_ATOMS * sizeof(ushort);
  ushort* xt    = (ushort*)w; w += (size_t)FDIM * N_ATOMS * sizeof(ushort);
  ushort* h1t   = (ushort*)w; w += (size_t)HID * N_ATOMS * sizeof(ushort);
  ushort* cat2  = (ushort*)w; w += (size_t)N_ATOMS * 1024 * sizeof(ushort);
  ushort* wcat2 = (ushort*)w; w += (size_t)HID * 1024 * sizeof(ushort);
  ushort* wb    = (ushort*)w; w += (size_t)64 * HID * sizeof(ushort);
  ushort* h2b   = (ushort*)w; w += (size_t)N_ATOMS * HID * sizeof(ushort);
  float*  sl    = (float*)w;  w += (size_t)4 * N_ATOMS * HID * sizeof(float);
  // sl (32 MB) reused: agg1 slices (16 x 4096 x 32), agg2 slices (4 x 8 MB),
  // h2 slices (2 x 8 MB).

  float* atom_out = (float*)d_out;
  float* bond_out = (float*)d_out + (size_t)N_ATOMS * FDIM;

  prep_adj<<<N_ATOMS, 256, 0, stream>>>(adj, adjb, rdeg);
  prep_misc<<<(N_ATOMS * FDIM + HID * 1024 + 64 * HID) / 256, 256, 0, stream>>>(
      x, xt, w_self2, w_neigh2, wcat2, w_atom, w_bond, wb);

  // agg1 slices: M=4096 N=32 K=4096, split-K=16 -> 512 blocks (2/CU)
  gemm_nt<128, 32, 4, 1, 1, 16, 0><<<512, 256, 0, stream>>>(
      adjb, N_ATOMS, xt, N_ATOMS, 256, sl, FDIM, (size_t)N_ATOMS * FDIM,
      nullptr, nullptr, nullptr, nullptr, nullptr);
  red_agg1<<<(N_ATOMS * FDIM / 4) / 256, 256, 0, stream>>>(sl, agg1);
  h1_kernel<<<(N_ATOMS * HID) / 256, 256, 0, stream>>>(
      x, agg1, rdeg, w_self1, b_self1, w_neigh1, b_neigh1, cat2, h1t);
  // agg2 slices: M=4096 N=512 K=4096, split-K=4 -> 512 blocks
  gemm_nt<128, 128, 2, 2, 4, 4, 0><<<512, 256, 0, stream>>>(
      adjb, N_ATOMS, h1t, N_ATOMS, 1024, sl, HID, (size_t)N_ATOMS * HID,
      nullptr, nullptr, nullptr, nullptr, nullptr);
  epi_agg2<<<(N_ATOMS * HID / 4) / 256, 256, 0, stream>>>(sl, rdeg, cat2);
  // h2 slices: M=4096 N=512 K=1024, BN=64, split-K=2 -> 512 blocks
  gemm_nt<128, 64, 2, 2, 8, 2, 0><<<512, 256, 0, stream>>>(
      cat2, 1024, wcat2, 1024, 512, sl, HID, (size_t)N_ATOMS * HID,
      nullptr, nullptr, nullptr, nullptr, nullptr);
  epi_h2<<<(N_ATOMS * HID / 4) / 256, 256, 0, stream>>>(sl, b_self2, b_neigh2, h2b);
  // heads: M=4096 N=64(40 used) K=512 MFMA GEMM, MODE 3 epilogue, 32 blocks
  gemm_nt<128, 64, 2, 2, 1, 1, 3><<<32, 256, 0, stream>>>(
      h2b, HID, wb, HID, 512, sl, HID, 0,
      b_atom, b_bond, atom_out, a_buf, b_buf);
  bond_fill<<<(N_ATOMS * N_ATOMS) / 256, 256, 0, stream>>>(a_buf, b_buf, bond_out);
}